// Round 1
// baseline (12915.057 us; speedup 1.0000x reference)
//
#include <hip/hip_runtime.h>
#include <hip/hip_bf16.h>

// ---------------- problem dims ----------------
#define B_   128   // batch
#define S_   512   // seq len
#define I_   512   // input dim
#define H_   1024  // hidden
#define G_   4096  // 4*H
#define O_   128   // output dim
#define NWG  128   // persistent workgroups (1/CU; 128 <= 256 CUs -> all co-resident)
#define HU   8     // hidden units per WG = H_/NWG

typedef short bf16x8 __attribute__((ext_vector_type(8)));
typedef float f32x4  __attribute__((ext_vector_type(4)));
typedef unsigned short u16;

__device__ __forceinline__ u16 f2bf(float f){
  union { float f; unsigned u; } v; v.f = f;
  unsigned r = v.u + 0x7fffu + ((v.u >> 16) & 1u);   // RTNE
  return (u16)(r >> 16);
}
__device__ __forceinline__ float sigm(float x){ return 1.0f/(1.0f + __expf(-x)); }
__device__ __forceinline__ float tanhfast(float x){ return 1.0f - 2.0f/(1.0f + __expf(2.0f*x)); }

// ---------------- prep kernels ----------------
__global__ void cast_f32_bf16(const float* __restrict__ src, u16* __restrict__ dst, int n4){
  int i = blockIdx.x*blockDim.x + threadIdx.x;
  const int st = gridDim.x*blockDim.x;
  for (; i < n4; i += st){
    float4 v = ((const float4*)src)[i];
    ushort4 o = make_ushort4(f2bf(v.x), f2bf(v.y), f2bf(v.z), f2bf(v.w));
    ((ushort4*)dst)[i] = o;
  }
}

__global__ void prep_bias(const float* __restrict__ bih, const float* __restrict__ bhh,
                          float* __restrict__ bc){
  int i = blockIdx.x*blockDim.x + threadIdx.x;
  if (i < G_) bc[i] = bih[i] + bhh[i];
}

// ---------------- grid barrier (agent scope; sense via generation counter) ----------------
__device__ __forceinline__ void gridbar(unsigned* __restrict__ bar){
  __syncthreads();                      // drains this WG's vmem (stores complete) before arrive
  if (threadIdx.x == 0){
    unsigned g = __hip_atomic_load(bar+1, __ATOMIC_RELAXED, __HIP_MEMORY_SCOPE_AGENT);
    unsigned a = __hip_atomic_fetch_add(bar, 1u, __ATOMIC_ACQ_REL, __HIP_MEMORY_SCOPE_AGENT);
    if (a == NWG-1u){
      __hip_atomic_store(bar,   0u,   __ATOMIC_RELAXED, __HIP_MEMORY_SCOPE_AGENT);
      __hip_atomic_store(bar+1, g+1u, __ATOMIC_RELEASE, __HIP_MEMORY_SCOPE_AGENT);
    } else {
      while (__hip_atomic_load(bar+1, __ATOMIC_ACQUIRE, __HIP_MEMORY_SCOPE_AGENT) == g){
        __builtin_amdgcn_s_sleep(1);
      }
    }
  }
  __syncthreads();
}

// ---------------- persistent LSTM kernel ----------------
// Per WG: 8 hidden units -> 32 gate cols {i,f,g,o}x8. W slices staged in LDS once.
// Per step: gates[128,32] = [x_t | h] @ Wslice^T via mfma 16x16x32 bf16,
// wave w owns rows [32w,32w+32), both 16-col tiles (acc 2x2 frags).
// LDS pad +8 elems/row: col stride 1040B -> 4-bank offset/col -> conflict-free b128 reads.
__shared__ u16 wih_s[32*520];   // 33,280 B   [lc][512+8]
__shared__ u16 whh_s[32*1032];  // 66,048 B   [lc][1024+8]   total 99,328 B LDS

__global__ __launch_bounds__(256) void lstm_persist(
    const u16*   __restrict__ xbf,   // [B][S][I] bf16 (valid iff use_xbf)
    const float* __restrict__ xf,    // [B][S][I] f32
    const int use_xbf,
    const u16*   __restrict__ Wih,   // [G][I] bf16
    const u16*   __restrict__ Whh,   // [G][H] bf16
    const float* __restrict__ bias,  // [G]  (b_ih+b_hh)
    u16*         __restrict__ hbuf,  // [2][B][H] bf16 double buffer
    float*       __restrict__ hfin,  // [B][H] f32 final h
    const float* __restrict__ Wfc,   // [O][H]
    const float* __restrict__ bfc,   // [O]
    float*       __restrict__ out,   // [B][O]
    unsigned*    __restrict__ bar)
{
  const int wg = blockIdx.x, tid = threadIdx.x;
  const int wv = tid >> 6, lane = tid & 63;
  const int n = lane & 15, g4 = lane >> 4;
  const int u0 = wg * HU;
  const int rb = wv * 32;

  // local col lc in [0,32): gate q = (lc>>4)*2 + ((lc&15)>>3), unit u0+(lc&7)
  auto colmap = [&](int lc){ return (((lc>>4)<<1) + ((lc&15)>>3))*H_ + u0 + (lc&7); };

  // ---- stage W slices to LDS (once) ----
  for (int idx = tid; idx < 32*64; idx += 256){          // Wih: 32 rows x 64 16B-chunks
    int lc = idx >> 6, c8 = (idx & 63) * 8;
    *(bf16x8*)(&wih_s[lc*520 + c8]) = *(const bf16x8*)(Wih + (size_t)colmap(lc)*I_ + c8);
  }
  for (int idx = tid; idx < 32*128; idx += 256){         // Whh: 32 rows x 128 chunks
    int lc = idx >> 7, c8 = (idx & 127) * 8;
    *(bf16x8*)(&whh_s[lc*1032 + c8]) = *(const bf16x8*)(Whh + (size_t)colmap(lc)*H_ + c8);
  }
  // ---- zero h0 (each WG zeros one 1024-elem row) ----
  { int gi = (wg*256 + tid)*4;
    *(ushort4*)(hbuf + gi) = make_ushort4(0,0,0,0); }
  gridbar(bar);   // publish h0 (+LDS via syncthreads inside)

  const float bias0 = bias[(0*2 + (n>>3))*H_ + u0 + (n&7)];   // ct=0 col bias (i|f)
  const float bias1 = bias[(1*2 + (n>>3))*H_ + u0 + (n&7)];   // ct=1 col bias (g|o)
  float cst[4] = {0.f, 0.f, 0.f, 0.f};   // cell state: this lane's 4 (row,unit) slots

  const int hi = (n >> 3);               // 0 -> handles rt0 rows; 1 -> rt1 rows
  const int ucol = u0 + (n & 7);
  const int rbase = rb + hi*16 + g4*4;

  for (int t = 0; t < S_; ++t){
    const u16* __restrict__ hc = hbuf + (size_t)(t & 1)*(B_*H_);
    u16*       __restrict__ hn = hbuf + (size_t)((t+1) & 1)*(B_*H_);

    f32x4 z = {0.f,0.f,0.f,0.f};
    f32x4 acc00 = z, acc01 = z, acc10 = z, acc11 = z;   // [rt][ct]

    // ---- x part: K = 512 ----
    if (use_xbf){
      const u16* xr0 = xbf + (size_t)(rb + n)*(S_*I_) + (size_t)t*I_;
      const u16* xr1 = xr0 + (size_t)16*(S_*I_);
      #pragma unroll 4
      for (int ks = 0; ks < I_/32; ++ks){
        const int kk = ks*32 + g4*8;
        bf16x8 a0 = *(const bf16x8*)(xr0 + kk);
        bf16x8 a1 = *(const bf16x8*)(xr1 + kk);
        bf16x8 b0 = *(const bf16x8*)(&wih_s[n*520 + kk]);
        bf16x8 b1 = *(const bf16x8*)(&wih_s[(16+n)*520 + kk]);
        acc00 = __builtin_amdgcn_mfma_f32_16x16x32_bf16(a0, b0, acc00, 0, 0, 0);
        acc01 = __builtin_amdgcn_mfma_f32_16x16x32_bf16(a0, b1, acc01, 0, 0, 0);
        acc10 = __builtin_amdgcn_mfma_f32_16x16x32_bf16(a1, b0, acc10, 0, 0, 0);
        acc11 = __builtin_amdgcn_mfma_f32_16x16x32_bf16(a1, b1, acc11, 0, 0, 0);
      }
    } else {
      const float* xr0 = xf + (size_t)(rb + n)*(S_*I_) + (size_t)t*I_;
      const float* xr1 = xr0 + (size_t)16*(S_*I_);
      #pragma unroll 2
      for (int ks = 0; ks < I_/32; ++ks){
        const int kk = ks*32 + g4*8;
        float4 v0a = *(const float4*)(xr0 + kk), v0b = *(const float4*)(xr0 + kk + 4);
        float4 v1a = *(const float4*)(xr1 + kk), v1b = *(const float4*)(xr1 + kk + 4);
        bf16x8 a0, a1;
        a0[0]=(short)f2bf(v0a.x); a0[1]=(short)f2bf(v0a.y); a0[2]=(short)f2bf(v0a.z); a0[3]=(short)f2bf(v0a.w);
        a0[4]=(short)f2bf(v0b.x); a0[5]=(short)f2bf(v0b.y); a0[6]=(short)f2bf(v0b.z); a0[7]=(short)f2bf(v0b.w);
        a1[0]=(short)f2bf(v1a.x); a1[1]=(short)f2bf(v1a.y); a1[2]=(short)f2bf(v1a.z); a1[3]=(short)f2bf(v1a.w);
        a1[4]=(short)f2bf(v1b.x); a1[5]=(short)f2bf(v1b.y); a1[6]=(short)f2bf(v1b.z); a1[7]=(short)f2bf(v1b.w);
        bf16x8 b0 = *(const bf16x8*)(&wih_s[n*520 + kk]);
        bf16x8 b1 = *(const bf16x8*)(&wih_s[(16+n)*520 + kk]);
        acc00 = __builtin_amdgcn_mfma_f32_16x16x32_bf16(a0, b0, acc00, 0, 0, 0);
        acc01 = __builtin_amdgcn_mfma_f32_16x16x32_bf16(a0, b1, acc01, 0, 0, 0);
        acc10 = __builtin_amdgcn_mfma_f32_16x16x32_bf16(a1, b0, acc10, 0, 0, 0);
        acc11 = __builtin_amdgcn_mfma_f32_16x16x32_bf16(a1, b1, acc11, 0, 0, 0);
      }
    }

    // ---- h part: K = 1024 ----
    {
      const u16* hr0 = hc + (size_t)(rb + n)*H_;
      const u16* hr1 = hc + (size_t)(rb + 16 + n)*H_;
      #pragma unroll 8
      for (int ks = 0; ks < H_/32; ++ks){
        const int kk = ks*32 + g4*8;
        bf16x8 a0 = *(const bf16x8*)(hr0 + kk);
        bf16x8 a1 = *(const bf16x8*)(hr1 + kk);
        bf16x8 b0 = *(const bf16x8*)(&whh_s[n*1032 + kk]);
        bf16x8 b1 = *(const bf16x8*)(&whh_s[(16+n)*1032 + kk]);
        acc00 = __builtin_amdgcn_mfma_f32_16x16x32_bf16(a0, b0, acc00, 0, 0, 0);
        acc01 = __builtin_amdgcn_mfma_f32_16x16x32_bf16(a0, b1, acc01, 0, 0, 0);
        acc10 = __builtin_amdgcn_mfma_f32_16x16x32_bf16(a1, b0, acc10, 0, 0, 0);
        acc11 = __builtin_amdgcn_mfma_f32_16x16x32_bf16(a1, b1, acc11, 0, 0, 0);
      }
    }

    // ---- gates / state update ----
    // D layout (verified m89/m91): col = lane&15, row = (lane>>4)*4 + reg.
    // ct0 cols: n<8 -> i-gate, n>=8 -> f-gate; ct1: g-gate / o-gate.
    // Low 8-lane half processes rt0 rows, high half rt1 (halves transcendental work).
    #pragma unroll
    for (int reg = 0; reg < 4; ++reg){
      float p00 = acc00[reg] + bias0;
      float p01 = acc01[reg] + bias1;
      float p10 = acc10[reg] + bias0;
      float p11 = acc11[reg] + bias1;
      float q00 = __shfl_xor(p00, 8);
      float q01 = __shfl_xor(p01, 8);
      float q10 = __shfl_xor(p10, 8);
      float q11 = __shfl_xor(p11, 8);
      float ip = hi ? q10 : p00;    // i-gate preact for (RT rows, unit ucol)
      float fp = hi ? p10 : q00;
      float gp = hi ? q11 : p01;
      float op = hi ? p11 : q01;
      float iv = sigm(ip), fv = sigm(fp), gv = tanhfast(gp), ov = sigm(op);
      float c = fv*cst[reg] + iv*gv;
      cst[reg] = c;
      float h = ov * tanhfast(c);
      const int r = rbase + reg;
      hn[(size_t)r*H_ + ucol] = f2bf(h);
      if (t == S_-1) hfin[(size_t)r*H_ + ucol] = h;
    }

    gridbar(bar);   // publish hn before anyone reads it at step t+1
  }

  // ---- fused FC epilogue: out[b] = hfin[b] @ Wfc^T + bfc, b = wg ----
  {
    const int b = wg;
    const int o = tid >> 1, half = tid & 1;
    const float4* hv = (const float4*)(hfin + (size_t)b*H_ + half*512);
    const float4* wvp = (const float4*)(Wfc + (size_t)o*H_ + half*512);
    float s = 0.f;
    #pragma unroll 8
    for (int j = 0; j < 128; ++j){
      float4 a = hv[j], w = wvp[j];
      s += a.x*w.x + a.y*w.y + a.z*w.z + a.w*w.w;
    }
    s += __shfl_xor(s, 1);
    if (half == 0) out[(size_t)b*O_ + o] = s + bfc[o];
  }
}

// ---------------- launcher ----------------
// ws layout (256-aligned):
//   [0)          Wih bf16   4,194,304
//   [4194304)    Whh bf16   8,388,608
//   [12582912)   bias f32      16,384
//   [12599296)   hbuf bf16    524,288
//   [13123584)   hfin f32     524,288
//   [13647872)   barrier          256
//   [13648128)   x bf16    67,108,864   (optional: only if ws_size allows)
extern "C" void kernel_launch(void* const* d_in, const int* in_sizes, int n_in,
                              void* d_out, int out_size, void* d_ws, size_t ws_size,
                              hipStream_t stream) {
  const float* x   = (const float*)d_in[0];
  const float* Wih = (const float*)d_in[1];
  const float* Whh = (const float*)d_in[2];
  const float* bih = (const float*)d_in[3];
  const float* bhh = (const float*)d_in[4];
  const float* Wfc = (const float*)d_in[5];
  const float* bfc = (const float*)d_in[6];
  float* out = (float*)d_out;

  char* ws = (char*)d_ws;
  u16*      wih_bf = (u16*)     (ws + 0);
  u16*      whh_bf = (u16*)     (ws + 4194304);
  float*    biasc  = (float*)   (ws + 12582912);
  u16*      hbuf   = (u16*)     (ws + 12599296);
  float*    hfin   = (float*)   (ws + 13123584);
  unsigned* bar    = (unsigned*)(ws + 13647872);
  u16*      xbf    = (u16*)     (ws + 13648128);
  const int use_xbf = (ws_size >= (size_t)13648128 + 67108864) ? 1 : 0;

  hipMemsetAsync(bar, 0, 256, stream);
  cast_f32_bf16<<<1024, 256, 0, stream>>>(Wih, wih_bf, (G_*I_)/4);
  cast_f32_bf16<<<2048, 256, 0, stream>>>(Whh, whh_bf, (G_*H_)/4);
  prep_bias<<<16, 256, 0, stream>>>(bih, bhh, biasc);
  if (use_xbf)
    cast_f32_bf16<<<2048, 256, 0, stream>>>(x, xbf, (B_*S_*I_)/4);

  lstm_persist<<<NWG, 256, 0, stream>>>(xbf, x, use_xbf, wih_bf, whh_bf, biasc,
                                        hbuf, hfin, Wfc, bfc, out, bar);
}

// Round 2
// 11248.119 us; speedup vs baseline: 1.1482x; 1.1482x over previous
//
#include <hip/hip_runtime.h>
#include <hip/hip_bf16.h>

// ---------------- problem dims ----------------
#define B_   128   // batch
#define S_   512   // seq len
#define I_   512   // input dim
#define H_   1024  // hidden
#define G_   4096  // 4*H
#define O_   128   // output dim
#define NWG  128   // persistent workgroups (1/CU)
#define HU   8     // hidden units per WG = H_/NWG

typedef short bf16x8 __attribute__((ext_vector_type(8)));
typedef float f32x4  __attribute__((ext_vector_type(4)));
typedef unsigned short u16;
typedef unsigned long long u64;

__device__ __forceinline__ u16 f2bf(float f){
  union { float f; unsigned u; } v; v.f = f;
  unsigned r = v.u + 0x7fffu + ((v.u >> 16) & 1u);   // RTNE
  return (u16)(r >> 16);
}
__device__ __forceinline__ float sigm(float x){ return 1.0f/(1.0f + __expf(-x)); }
__device__ __forceinline__ float tanhfast(float x){ return 1.0f - 2.0f/(1.0f + __expf(2.0f*x)); }

// relaxed agent-scope coherent ops: write-through / L2-bypass, NO wb/inv fences
__device__ __forceinline__ void coh_store64(u16* p, u64 v){
  __hip_atomic_store((u64*)p, v, __ATOMIC_RELAXED, __HIP_MEMORY_SCOPE_AGENT);
}
__device__ __forceinline__ u64 coh_load64(const u16* p){
  return __hip_atomic_load((u64*)p, __ATOMIC_RELAXED, __HIP_MEMORY_SCOPE_AGENT);
}
__device__ __forceinline__ bf16x8 coh_load_bf8(const u16* p){
  union { u64 q[2]; bf16x8 v; } ua;
  ua.q[0] = __hip_atomic_load((u64*)p,     __ATOMIC_RELAXED, __HIP_MEMORY_SCOPE_AGENT);
  ua.q[1] = __hip_atomic_load((u64*)p + 1, __ATOMIC_RELAXED, __HIP_MEMORY_SCOPE_AGENT);
  return ua.v;
}

// ---------------- prep kernels ----------------
__global__ void cast_f32_bf16(const float* __restrict__ src, u16* __restrict__ dst, int n4){
  int i = blockIdx.x*blockDim.x + threadIdx.x;
  const int st = gridDim.x*blockDim.x;
  for (; i < n4; i += st){
    float4 v = ((const float4*)src)[i];
    ushort4 o = make_ushort4(f2bf(v.x), f2bf(v.y), f2bf(v.z), f2bf(v.w));
    ((ushort4*)dst)[i] = o;
  }
}

__global__ void prep_bias(const float* __restrict__ bih, const float* __restrict__ bhh,
                          float* __restrict__ bc){
  int i = blockIdx.x*blockDim.x + threadIdx.x;
  if (i < G_) bc[i] = bih[i] + bhh[i];
}

// ---------------- persistent LSTM kernel ----------------
// Per WG: 8 hidden units -> 32 gate cols {i,f,g,o}x8. W slices staged in LDS once.
// Per step: gates[128,32] = [x_t | h] @ Wslice^T via mfma 16x16x32 bf16.
// Monotonic barrier: RELAXED atomics only (no L2 wb/inv). h/hfin cross-WG data
// moves via relaxed agent-scope atomic b64 (LLC-coherent, no cache sweeps).
__shared__ u16 wih_s[32*520];   // 33,280 B   [lc][512+8]
__shared__ u16 whh_s[32*1032];  // 66,048 B   [lc][1024+8]   total 99,328 B LDS

__global__ __launch_bounds__(256) void lstm_persist(
    const u16*   __restrict__ xbf,   // [B][S][I] bf16 (valid iff use_xbf)
    const float* __restrict__ xf,    // [B][S][I] f32
    const int use_xbf,
    const u16*   __restrict__ Wih,   // [G][I] bf16
    const u16*   __restrict__ Whh,   // [G][H] bf16
    const float* __restrict__ bias,  // [G]  (b_ih+b_hh)
    u16*         __restrict__ hbuf,  // [2][B][H] bf16 double buffer
    float*       __restrict__ hfin,  // [B][H] f32 final h
    const float* __restrict__ Wfc,   // [O][H]
    const float* __restrict__ bfc,   // [O]
    float*       __restrict__ out,   // [B][O]
    unsigned*    __restrict__ bar)
{
  const int wg = blockIdx.x, tid = threadIdx.x;
  const int wv = tid >> 6, lane = tid & 63;
  const int n = lane & 15, g4 = lane >> 4;
  const int u0 = wg * HU;
  const int rb = wv * 32;

  auto colmap = [&](int lc){ return (((lc>>4)<<1) + ((lc&15)>>3))*H_ + u0 + (lc&7); };

  // ---- stage W slices to LDS (once) ----
  for (int idx = tid; idx < 32*64; idx += 256){
    int lc = idx >> 6, c8 = (idx & 63) * 8;
    *(bf16x8*)(&wih_s[lc*520 + c8]) = *(const bf16x8*)(Wih + (size_t)colmap(lc)*I_ + c8);
  }
  for (int idx = tid; idx < 32*128; idx += 256){
    int lc = idx >> 7, c8 = (idx & 127) * 8;
    *(bf16x8*)(&whh_s[lc*1032 + c8]) = *(const bf16x8*)(Whh + (size_t)colmap(lc)*H_ + c8);
  }
  // ---- zero h0 row wg (coherent stores so step-0 atomic loads see zeros) ----
  if (tid < 128) coh_store64(hbuf + (size_t)wg*H_ + tid*4, 0ull);

  // arrival #1 (h0 published)
  asm volatile("s_waitcnt vmcnt(0)" ::: "memory");
  __syncthreads();
  if (tid == 0) __hip_atomic_fetch_add(bar, 1u, __ATOMIC_RELAXED, __HIP_MEMORY_SCOPE_AGENT);

  const float bias0 = bias[(0*2 + (n>>3))*H_ + u0 + (n&7)];
  const float bias1 = bias[(1*2 + (n>>3))*H_ + u0 + (n&7)];
  float cst[4] = {0.f, 0.f, 0.f, 0.f};

  const int hi = (n >> 3);
  const int ucol = u0 + (n & 7);
  const int rbase = rb + hi*16 + g4*4;

  const f32x4 z = {0.f,0.f,0.f,0.f};
  f32x4 ax00, ax01, ax10, ax11;    // x-part accumulators (precomputed pre-barrier)

  // ---- x-part precompute lambda (no h dependency) ----
  auto xpart = [&](int t){
    ax00 = z; ax01 = z; ax10 = z; ax11 = z;
    if (use_xbf){
      const u16* xr0 = xbf + (size_t)(rb + n)*(S_*I_) + (size_t)t*I_;
      const u16* xr1 = xr0 + (size_t)16*(S_*I_);
      #pragma unroll 4
      for (int ks = 0; ks < I_/32; ++ks){
        const int kk = ks*32 + g4*8;
        bf16x8 a0 = *(const bf16x8*)(xr0 + kk);
        bf16x8 a1 = *(const bf16x8*)(xr1 + kk);
        bf16x8 b0 = *(const bf16x8*)(&wih_s[n*520 + kk]);
        bf16x8 b1 = *(const bf16x8*)(&wih_s[(16+n)*520 + kk]);
        ax00 = __builtin_amdgcn_mfma_f32_16x16x32_bf16(a0, b0, ax00, 0, 0, 0);
        ax01 = __builtin_amdgcn_mfma_f32_16x16x32_bf16(a0, b1, ax01, 0, 0, 0);
        ax10 = __builtin_amdgcn_mfma_f32_16x16x32_bf16(a1, b0, ax10, 0, 0, 0);
        ax11 = __builtin_amdgcn_mfma_f32_16x16x32_bf16(a1, b1, ax11, 0, 0, 0);
      }
    } else {
      const float* xr0 = xf + (size_t)(rb + n)*(S_*I_) + (size_t)t*I_;
      const float* xr1 = xr0 + (size_t)16*(S_*I_);
      #pragma unroll 2
      for (int ks = 0; ks < I_/32; ++ks){
        const int kk = ks*32 + g4*8;
        float4 v0a = *(const float4*)(xr0 + kk), v0b = *(const float4*)(xr0 + kk + 4);
        float4 v1a = *(const float4*)(xr1 + kk), v1b = *(const float4*)(xr1 + kk + 4);
        bf16x8 a0, a1;
        a0[0]=(short)f2bf(v0a.x); a0[1]=(short)f2bf(v0a.y); a0[2]=(short)f2bf(v0a.z); a0[3]=(short)f2bf(v0a.w);
        a0[4]=(short)f2bf(v0b.x); a0[5]=(short)f2bf(v0b.y); a0[6]=(short)f2bf(v0b.z); a0[7]=(short)f2bf(v0b.w);
        a1[0]=(short)f2bf(v1a.x); a1[1]=(short)f2bf(v1a.y); a1[2]=(short)f2bf(v1a.z); a1[3]=(short)f2bf(v1a.w);
        a1[4]=(short)f2bf(v1b.x); a1[5]=(short)f2bf(v1b.y); a1[6]=(short)f2bf(v1b.z); a1[7]=(short)f2bf(v1b.w);
        bf16x8 b0 = *(const bf16x8*)(&wih_s[n*520 + kk]);
        bf16x8 b1 = *(const bf16x8*)(&wih_s[(16+n)*520 + kk]);
        ax00 = __builtin_amdgcn_mfma_f32_16x16x32_bf16(a0, b0, ax00, 0, 0, 0);
        ax01 = __builtin_amdgcn_mfma_f32_16x16x32_bf16(a0, b1, ax01, 0, 0, 0);
        ax10 = __builtin_amdgcn_mfma_f32_16x16x32_bf16(a1, b0, ax10, 0, 0, 0);
        ax11 = __builtin_amdgcn_mfma_f32_16x16x32_bf16(a1, b1, ax11, 0, 0, 0);
      }
    }
  };

  xpart(0);          // overlaps other WGs' init
  unsigned tgt = NWG;

  for (int t = 0; t < S_; ++t){
    const u16* __restrict__ hc = hbuf + (size_t)(t & 1)*(B_*H_);
    u16*       __restrict__ hn = hbuf + (size_t)((t+1) & 1)*(B_*H_);

    // ---- wait: h_t published (count >= (t+1)*NWG) ----
    if (tid == 0){
      while (__hip_atomic_load(bar, __ATOMIC_RELAXED, __HIP_MEMORY_SCOPE_AGENT) < tgt)
        __builtin_amdgcn_s_sleep(1);
    }
    __syncthreads();

    f32x4 acc00 = ax00, acc01 = ax01, acc10 = ax10, acc11 = ax11;

    // ---- h part: K = 1024, coherent A-loads (LLC) ----
    {
      const u16* hr0 = hc + (size_t)(rb + n)*H_;
      const u16* hr1 = hc + (size_t)(rb + 16 + n)*H_;
      #pragma unroll 8
      for (int ks = 0; ks < H_/32; ++ks){
        const int kk = ks*32 + g4*8;
        bf16x8 a0 = coh_load_bf8(hr0 + kk);
        bf16x8 a1 = coh_load_bf8(hr1 + kk);
        bf16x8 b0 = *(const bf16x8*)(&whh_s[n*1032 + kk]);
        bf16x8 b1 = *(const bf16x8*)(&whh_s[(16+n)*1032 + kk]);
        acc00 = __builtin_amdgcn_mfma_f32_16x16x32_bf16(a0, b0, acc00, 0, 0, 0);
        acc01 = __builtin_amdgcn_mfma_f32_16x16x32_bf16(a0, b1, acc01, 0, 0, 0);
        acc10 = __builtin_amdgcn_mfma_f32_16x16x32_bf16(a1, b0, acc10, 0, 0, 0);
        acc11 = __builtin_amdgcn_mfma_f32_16x16x32_bf16(a1, b1, acc11, 0, 0, 0);
      }
    }

    // ---- gates / state update (D layout: col=lane&15, row=(lane>>4)*4+reg) ----
    #pragma unroll
    for (int reg = 0; reg < 4; ++reg){
      float p00 = acc00[reg] + bias0;
      float p01 = acc01[reg] + bias1;
      float p10 = acc10[reg] + bias0;
      float p11 = acc11[reg] + bias1;
      float q00 = __shfl_xor(p00, 8);
      float q01 = __shfl_xor(p01, 8);
      float q10 = __shfl_xor(p10, 8);
      float q11 = __shfl_xor(p11, 8);
      float ip = hi ? q10 : p00;
      float fp = hi ? p10 : q00;
      float gp = hi ? q11 : p01;
      float op = hi ? p11 : q01;
      float iv = sigm(ip), fv = sigm(fp), gv = tanhfast(gp), ov = sigm(op);
      float c = fv*cst[reg] + iv*gv;
      cst[reg] = c;
      float h = ov * tanhfast(c);
      const int r = rbase + reg;

      // pack 4 cols -> one coherent b64 store (lanes n%4==0)
      unsigned v16 = f2bf(h);
      unsigned pr  = v16 | (__shfl_xor(v16, 1) << 16);
      unsigned pr2 = __shfl_xor(pr, 2);
      if ((n & 3) == 0){
        u64 q = (u64)pr | ((u64)pr2 << 32);
        coh_store64(hn + (size_t)r*H_ + u0 + (n & 4), q);
      }
      if (t == S_-1){
        unsigned fb = __float_as_uint(h);
        unsigned fo = __shfl_xor(fb, 1);
        if ((n & 1) == 0){
          u64 q = (u64)fb | ((u64)fo << 32);
          __hip_atomic_store((u64*)(hfin + (size_t)r*H_ + u0 + (n & 7)), q,
                             __ATOMIC_RELAXED, __HIP_MEMORY_SCOPE_AGENT);
        }
      }
    }

    // ---- arrive (stores drained per-wave first) ----
    asm volatile("s_waitcnt vmcnt(0)" ::: "memory");
    __syncthreads();
    if (tid == 0) __hip_atomic_fetch_add(bar, 1u, __ATOMIC_RELAXED, __HIP_MEMORY_SCOPE_AGENT);
    tgt += NWG;

    // ---- x-part for t+1 overlaps stragglers ----
    if (t < S_-1) xpart(t+1);
  }

  // ---- final wait: hfin fully published ----
  if (tid == 0){
    while (__hip_atomic_load(bar, __ATOMIC_RELAXED, __HIP_MEMORY_SCOPE_AGENT) < tgt)
      __builtin_amdgcn_s_sleep(1);
  }
  __syncthreads();

  // ---- fused FC epilogue: out[b] = hfin[b] @ Wfc^T + bfc, b = wg ----
  {
    const int b = wg;
    const int o = tid >> 1, half = tid & 1;
    const float* hb = hfin + (size_t)b*H_ + half*512;
    const float* wb = Wfc + (size_t)o*H_ + half*512;
    float s = 0.f;
    #pragma unroll 8
    for (int j = 0; j < 256; ++j){
      u64 q = __hip_atomic_load((u64*)(hb + j*2), __ATOMIC_RELAXED, __HIP_MEMORY_SCOPE_AGENT);
      float a0 = __uint_as_float((unsigned)q);
      float a1 = __uint_as_float((unsigned)(q >> 32));
      float2 w = *(const float2*)(wb + j*2);
      s += a0*w.x + a1*w.y;
    }
    s += __shfl_xor(s, 1);
    if (half == 0) out[(size_t)b*O_ + o] = s + bfc[o];
  }
}

// ---------------- launcher ----------------
extern "C" void kernel_launch(void* const* d_in, const int* in_sizes, int n_in,
                              void* d_out, int out_size, void* d_ws, size_t ws_size,
                              hipStream_t stream) {
  const float* x   = (const float*)d_in[0];
  const float* Wih = (const float*)d_in[1];
  const float* Whh = (const float*)d_in[2];
  const float* bih = (const float*)d_in[3];
  const float* bhh = (const float*)d_in[4];
  const float* Wfc = (const float*)d_in[5];
  const float* bfc = (const float*)d_in[6];
  float* out = (float*)d_out;

  char* ws = (char*)d_ws;
  u16*      wih_bf = (u16*)     (ws + 0);
  u16*      whh_bf = (u16*)     (ws + 4194304);
  float*    biasc  = (float*)   (ws + 12582912);
  u16*      hbuf   = (u16*)     (ws + 12599296);
  float*    hfin   = (float*)   (ws + 13123584);
  unsigned* bar    = (unsigned*)(ws + 13647872);
  u16*      xbf    = (u16*)     (ws + 13648128);
  const int use_xbf = (ws_size >= (size_t)13648128 + 67108864) ? 1 : 0;

  hipMemsetAsync(bar, 0, 256, stream);
  cast_f32_bf16<<<1024, 256, 0, stream>>>(Wih, wih_bf, (G_*I_)/4);
  cast_f32_bf16<<<2048, 256, 0, stream>>>(Whh, whh_bf, (G_*H_)/4);
  prep_bias<<<16, 256, 0, stream>>>(bih, bhh, biasc);
  if (use_xbf)
    cast_f32_bf16<<<2048, 256, 0, stream>>>(x, xbf, (B_*S_*I_)/4);

  lstm_persist<<<NWG, 256, 0, stream>>>(xbf, x, use_xbf, wih_bf, whh_bf, biasc,
                                        hbuf, hfin, Wfc, bfc, out, bar);
}

// Round 4
// 4748.345 us; speedup vs baseline: 2.7199x; 2.3689x over previous
//
#include <hip/hip_runtime.h>
#include <hip/hip_bf16.h>

// ---------------- problem dims ----------------
#define B_   128   // batch
#define S_   512   // seq len
#define I_   512   // input dim
#define H_   1024  // hidden
#define G_   4096  // 4*H
#define O_   128   // output dim
#define NWG  256   // 2 batch-halves x 128 col-groups, 1 WG/CU on 256 CUs
#define HU   8     // hidden units per col-group

typedef short bf16x8 __attribute__((ext_vector_type(8)));
typedef float f32x4  __attribute__((ext_vector_type(4)));
typedef unsigned short u16;
typedef unsigned long long u64;

__device__ __forceinline__ u16 f2bf(float f){
  union { float f; unsigned u; } v; v.f = f;
  unsigned r = v.u + 0x7fffu + ((v.u >> 16) & 1u);   // RTNE
  return (u16)(r >> 16);
}
__device__ __forceinline__ float sigm(float x){ return 1.0f/(1.0f + __expf(-x)); }
__device__ __forceinline__ float tanhfast(float x){ return 1.0f - 2.0f/(1.0f + __expf(2.0f*x)); }

// relaxed agent-scope coherent ops (write-through / cache-bypass, no wb/inv)
__device__ __forceinline__ void coh_store64(u16* p, u64 v){
  __hip_atomic_store((u64*)p, v, __ATOMIC_RELAXED, __HIP_MEMORY_SCOPE_AGENT);
}
__device__ __forceinline__ u64 coh_load64(const void* p){
  return __hip_atomic_load((const u64*)p, __ATOMIC_RELAXED, __HIP_MEMORY_SCOPE_AGENT);
}

// coherent b128 load, L1+L2 bypass (sc0 sc1). vmcnt is MANUALLY managed by the
// caller (counted waits) — compiler does not track these.
#define HL(dst, boff) \
  asm volatile("global_load_dwordx4 %0, %1, off offset:" boff " sc0 sc1" \
               : "=v"(dst) : "v"(haddr) : "memory");

#define MF(a,b,c) __builtin_amdgcn_mfma_f32_16x16x32_bf16((a),(b),(c),0,0,0)

// ---------------- prep kernels ----------------
__global__ void cast_f32_bf16(const float* __restrict__ src, u16* __restrict__ dst, int n4){
  int i = blockIdx.x*blockDim.x + threadIdx.x;
  const int st = gridDim.x*blockDim.x;
  for (; i < n4; i += st){
    float4 v = ((const float4*)src)[i];
    ushort4 o = make_ushort4(f2bf(v.x), f2bf(v.y), f2bf(v.z), f2bf(v.w));
    ((ushort4*)dst)[i] = o;
  }
}

__global__ void prep_bias(const float* __restrict__ bih, const float* __restrict__ bhh,
                          float* __restrict__ bc){
  int i = blockIdx.x*blockDim.x + threadIdx.x;
  if (i < G_) bc[i] = bih[i] + bhh[i];
}

// ---------------- persistent LSTM kernel ----------------
// wg = bh*128 + cg : batch-half bh (64 rows), col-group cg (8 units -> 32 gate cols).
// Per step per CU: gates[64,32] = [x_t | h][64,1536] @ Wslice^T, mfma 16x16x32 bf16,
// wave wv owns 16 rows. h broadcast via LLC with coherent b128 loads, double-banked
// counted-vmcnt pipeline (16KB/wave in flight). Monotonic relaxed grid barrier.
__shared__ u16 wih_s[32*520];   // 33,280 B   [lc][512+8]
__shared__ u16 whh_s[32*1032];  // 66,048 B   [lc][1024+8]   total 99,328 B LDS

__global__ __launch_bounds__(256) void lstm_persist(
    const u16*   __restrict__ xbf,   // [B][S][I] bf16 (valid iff use_xbf)
    const float* __restrict__ xf,    // [B][S][I] f32
    const int use_xbf,
    const u16*   __restrict__ Wih,   // [G][I] bf16
    const u16*   __restrict__ Whh,   // [G][H] bf16
    const float* __restrict__ bias,  // [G]  (b_ih+b_hh)
    u16*         __restrict__ hbuf,  // [2][B][H] bf16 double buffer
    float*       __restrict__ hfin,  // [B][H] f32 final h
    const float* __restrict__ Wfc,   // [O][H]
    const float* __restrict__ bfc,   // [O]
    float*       __restrict__ out,   // [B][O]
    unsigned*    __restrict__ bar)
{
  const int wg = blockIdx.x, tid = threadIdx.x;
  const int bh = wg >> 7;            // batch half: rows [bh*64, bh*64+64)
  const int cg = wg & 127;           // col group
  const int wv = tid >> 6, lane = tid & 63;
  const int n = lane & 15, g4 = lane >> 4;
  const int u0 = cg * HU;
  const int rb = bh*64 + wv*16;      // this wave's 16 batch rows

  auto colmap = [&](int lc){ return (((lc>>4)<<1) + ((lc&15)>>3))*H_ + u0 + (lc&7); };

  // ---- stage W slices to LDS (once) ----
  for (int idx = tid; idx < 32*64; idx += 256){
    int lc = idx >> 6, c8 = (idx & 63) * 8;
    *(bf16x8*)(&wih_s[lc*520 + c8]) = *(const bf16x8*)(Wih + (size_t)colmap(lc)*I_ + c8);
  }
  for (int idx = tid; idx < 32*128; idx += 256){
    int lc = idx >> 7, c8 = (idx & 127) * 8;
    *(bf16x8*)(&whh_s[lc*1032 + c8]) = *(const bf16x8*)(Whh + (size_t)colmap(lc)*H_ + c8);
  }
  // ---- zero h0: this CU's output region rows [bh*64,+64) x units [u0,+8) ----
  if (tid < 64){
    u16* p = hbuf + (size_t)(bh*64 + tid)*H_ + u0;
    coh_store64(p, 0ull); coh_store64(p + 4, 0ull);
  }
  asm volatile("s_waitcnt vmcnt(0)" ::: "memory");
  __syncthreads();
  if (tid == 0) __hip_atomic_fetch_add(bar, 1u, __ATOMIC_RELAXED, __HIP_MEMORY_SCOPE_AGENT);

  const float bias0 = bias[(0*2 + (n>>3))*H_ + u0 + (n&7)];   // ct0: i|f
  const float bias1 = bias[(1*2 + (n>>3))*H_ + u0 + (n&7)];   // ct1: g|o
  float cst[4] = {0.f, 0.f, 0.f, 0.f};
  const int hi = (n >> 3);
  const f32x4 z = {0.f,0.f,0.f,0.f};
  f32x4 ax0, ax1;   // x-part accumulators (precomputed, overlaps barrier wait)

  auto xpart = [&](int t){
    ax0 = z; ax1 = z;
    if (use_xbf){
      const u16* xr = xbf + (size_t)(rb + n)*(S_*I_) + (size_t)t*I_;
      #pragma unroll 4
      for (int ks = 0; ks < 16; ++ks){
        const int kk = ks*32 + g4*8;
        bf16x8 a  = *(const bf16x8*)(xr + kk);
        bf16x8 b0 = *(const bf16x8*)(&wih_s[n*520 + kk]);
        bf16x8 b1 = *(const bf16x8*)(&wih_s[(16+n)*520 + kk]);
        ax0 = MF(a, b0, ax0); ax1 = MF(a, b1, ax1);
      }
    } else {
      const float* xr = xf + (size_t)(rb + n)*(S_*I_) + (size_t)t*I_;
      #pragma unroll 2
      for (int ks = 0; ks < 16; ++ks){
        const int kk = ks*32 + g4*8;
        float4 va = *(const float4*)(xr + kk), vb = *(const float4*)(xr + kk + 4);
        bf16x8 a;
        a[0]=(short)f2bf(va.x); a[1]=(short)f2bf(va.y); a[2]=(short)f2bf(va.z); a[3]=(short)f2bf(va.w);
        a[4]=(short)f2bf(vb.x); a[5]=(short)f2bf(vb.y); a[6]=(short)f2bf(vb.z); a[7]=(short)f2bf(vb.w);
        bf16x8 b0 = *(const bf16x8*)(&wih_s[n*520 + kk]);
        bf16x8 b1 = *(const bf16x8*)(&wih_s[(16+n)*520 + kk]);
        ax0 = MF(a, b0, ax0); ax1 = MF(a, b1, ax1);
      }
    }
  };

  xpart(0);
  unsigned tgt = NWG;

  for (int t = 0; t < S_; ++t){
    const u16* __restrict__ hc = hbuf + (size_t)(t & 1)*(B_*H_);
    u16*       __restrict__ hn = hbuf + (size_t)((t+1) & 1)*(B_*H_);

    // ---- wait: h_t fully published ----
    if (tid == 0){
      while (__hip_atomic_load(bar, __ATOMIC_RELAXED, __HIP_MEMORY_SCOPE_AGENT) < tgt)
        __builtin_amdgcn_s_sleep(1);
    }
    __syncthreads();

    // ---- h part: K=1024, coherent b128 loads, 2-bank counted-vmcnt pipeline ----
    // lane reads row rb+n, chunk ks at byte offset ks*64 from haddr (g4*16 folded in).
    const u16* haddr = hc + (size_t)(rb + n)*H_ + g4*8;
    f32x4 acc0a = ax0, acc1a = ax1, acc0b = z, acc1b = z;
    bf16x8 hA0,hA1,hA2,hA3,hA4,hA5,hA6,hA7;
    bf16x8 hB0,hB1,hB2,hB3,hB4,hB5,hB6,hB7;

    #define CONS(hreg, ks) { \
      const int kk = (ks)*32 + g4*8; \
      bf16x8 bf0 = *(const bf16x8*)(&whh_s[n*1032 + kk]); \
      bf16x8 bf1 = *(const bf16x8*)(&whh_s[(16+n)*1032 + kk]); \
      if ((ks) & 1){ acc0b = MF(hreg, bf0, acc0b); acc1b = MF(hreg, bf1, acc1b); } \
      else         { acc0a = MF(hreg, bf0, acc0a); acc1a = MF(hreg, bf1, acc1a); } }
    #define CONS8(P, base) \
      CONS(P##0, (base)+0) CONS(P##1, (base)+1) CONS(P##2, (base)+2) CONS(P##3, (base)+3) \
      CONS(P##4, (base)+4) CONS(P##5, (base)+5) CONS(P##6, (base)+6) CONS(P##7, (base)+7)

    HL(hA0,"0")    HL(hA1,"64")   HL(hA2,"128")  HL(hA3,"192")
    HL(hA4,"256")  HL(hA5,"320")  HL(hA6,"384")  HL(hA7,"448")
    HL(hB0,"512")  HL(hB1,"576")  HL(hB2,"640")  HL(hB3,"704")
    HL(hB4,"768")  HL(hB5,"832")  HL(hB6,"896")  HL(hB7,"960")

    asm volatile("s_waitcnt vmcnt(8)" ::: "memory");   // bank A ready
    __builtin_amdgcn_sched_barrier(0);
    CONS8(hA, 0)
    HL(hA0,"1024") HL(hA1,"1088") HL(hA2,"1152") HL(hA3,"1216")
    HL(hA4,"1280") HL(hA5,"1344") HL(hA6,"1408") HL(hA7,"1472")

    asm volatile("s_waitcnt vmcnt(8)" ::: "memory");   // bank B ready
    __builtin_amdgcn_sched_barrier(0);
    CONS8(hB, 8)
    HL(hB0,"1536") HL(hB1,"1600") HL(hB2,"1664") HL(hB3,"1728")
    HL(hB4,"1792") HL(hB5,"1856") HL(hB6,"1920") HL(hB7,"1984")

    asm volatile("s_waitcnt vmcnt(8)" ::: "memory");   // bank A' ready
    __builtin_amdgcn_sched_barrier(0);
    CONS8(hA, 16)

    asm volatile("s_waitcnt vmcnt(0)" ::: "memory");   // bank B' ready (drain)
    __builtin_amdgcn_sched_barrier(0);
    CONS8(hB, 24)

    #undef CONS8
    #undef CONS

    f32x4 acc0 = acc0a + acc0b;
    f32x4 acc1 = acc1a + acc1b;

    // ---- gates / state update (D: col=lane&15, row=(lane>>4)*4+reg) ----
    #pragma unroll
    for (int reg = 0; reg < 4; ++reg){
      float p0 = acc0[reg] + bias0;     // ct0: n<8 -> i(unit n), n>=8 -> f(unit n-8)
      float p1 = acc1[reg] + bias1;     // ct1: g / o
      float q0 = __shfl_xor(p0, 8);
      float q1 = __shfl_xor(p1, 8);
      float ip = hi ? q0 : p0;
      float fp = hi ? p0 : q0;
      float gp = hi ? q1 : p1;
      float op = hi ? p1 : q1;
      float iv = sigm(ip), fv = sigm(fp), gv = tanhfast(gp), ov = sigm(op);
      float c = fv*cst[reg] + iv*gv;
      cst[reg] = c;
      float h = ov * tanhfast(c);
      const int r = rb + g4*4 + reg;

      unsigned v16 = f2bf(h);
      unsigned pr  = v16 | (__shfl_xor(v16, 1) << 16);
      unsigned pr2 = __shfl_xor(pr, 2);
      if (hi == 0 && (n & 3) == 0){                      // lanes 0,4: units n..n+3
        u64 q = (u64)pr | ((u64)pr2 << 32);
        coh_store64(hn + (size_t)r*H_ + u0 + n, q);
      }
      if (t == S_-1){
        unsigned fb = __float_as_uint(h);
        unsigned fo = __shfl_xor(fb, 1);
        if (hi == 0 && (n & 1) == 0){                    // lanes 0,2,4,6: f32 pairs
          u64 q = (u64)fb | ((u64)fo << 32);
          __hip_atomic_store((u64*)(hfin + (size_t)r*H_ + u0 + n), q,
                             __ATOMIC_RELAXED, __HIP_MEMORY_SCOPE_AGENT);
        }
      }
    }

    // ---- arrive (all stores ack'd at coherence point first) ----
    asm volatile("s_waitcnt vmcnt(0)" ::: "memory");
    __syncthreads();
    if (tid == 0) __hip_atomic_fetch_add(bar, 1u, __ATOMIC_RELAXED, __HIP_MEMORY_SCOPE_AGENT);
    tgt += NWG;

    if (t < S_-1) xpart(t+1);    // overlaps other WGs' straggle + barrier latency
  }

  // ---- final wait: hfin fully published ----
  if (tid == 0){
    while (__hip_atomic_load(bar, __ATOMIC_RELAXED, __HIP_MEMORY_SCOPE_AGENT) < tgt)
      __builtin_amdgcn_s_sleep(1);
  }
  __syncthreads();

  // ---- fused FC epilogue: out[b] = hfin[b] @ Wfc^T + bfc ----
  {
    const int b = wg & 127;
    const int o = (wg >> 7)*64 + (tid >> 2);
    const int qtr = tid & 3;
    const float* hb = hfin + (size_t)b*H_ + qtr*256;
    const float* wb = Wfc + (size_t)o*H_ + qtr*256;
    float s = 0.f;
    #pragma unroll 8
    for (int j = 0; j < 128; ++j){
      u64 q = coh_load64(hb + j*2);
      float a0 = __uint_as_float((unsigned)q);
      float a1 = __uint_as_float((unsigned)(q >> 32));
      float2 w = *(const float2*)(wb + j*2);
      s += a0*w.x + a1*w.y;
    }
    s += __shfl_xor(s, 1);
    s += __shfl_xor(s, 2);
    if (qtr == 0) out[(size_t)b*O_ + o] = s + bfc[o];
  }
}

// ---------------- launcher ----------------
extern "C" void kernel_launch(void* const* d_in, const int* in_sizes, int n_in,
                              void* d_out, int out_size, void* d_ws, size_t ws_size,
                              hipStream_t stream) {
  const float* x   = (const float*)d_in[0];
  const float* Wih = (const float*)d_in[1];
  const float* Whh = (const float*)d_in[2];
  const float* bih = (const float*)d_in[3];
  const float* bhh = (const float*)d_in[4];
  const float* Wfc = (const float*)d_in[5];
  const float* bfc = (const float*)d_in[6];
  float* out = (float*)d_out;

  char* ws = (char*)d_ws;
  u16*      wih_bf = (u16*)     (ws + 0);
  u16*      whh_bf = (u16*)     (ws + 4194304);
  float*    biasc  = (float*)   (ws + 12582912);
  u16*      hbuf   = (u16*)     (ws + 12599296);
  float*    hfin   = (float*)   (ws + 13123584);
  unsigned* bar    = (unsigned*)(ws + 13647872);
  u16*      xbf    = (u16*)     (ws + 13648128);
  const int use_xbf = (ws_size >= (size_t)13648128 + 67108864) ? 1 : 0;

  hipMemsetAsync(bar, 0, 256, stream);
  cast_f32_bf16<<<1024, 256, 0, stream>>>(Wih, wih_bf, (G_*I_)/4);
  cast_f32_bf16<<<2048, 256, 0, stream>>>(Whh, whh_bf, (G_*H_)/4);
  prep_bias<<<16, 256, 0, stream>>>(bih, bhh, biasc);
  if (use_xbf)
    cast_f32_bf16<<<2048, 256, 0, stream>>>(x, xbf, (B_*S_*I_)/4);

  lstm_persist<<<NWG, 256, 0, stream>>>(xbf, x, use_xbf, wih_bf, whh_bf, biasc,
                                        hbuf, hfin, Wfc, bfc, out, bar);
}

// Round 5
// 4699.375 us; speedup vs baseline: 2.7483x; 1.0104x over previous
//
#include <hip/hip_runtime.h>
#include <hip/hip_bf16.h>

// ---------------- problem dims ----------------
#define B_   128   // batch
#define S_   512   // seq len
#define I_   512   // input dim
#define H_   1024  // hidden
#define G_   4096  // 4*H
#define O_   128   // output dim
#define NWG  256   // 2 batch-halves x 128 col-groups, 1 WG/CU on 256 CUs
#define HU   8     // hidden units per col-group

typedef short bf16x8 __attribute__((ext_vector_type(8)));
typedef float f32x4  __attribute__((ext_vector_type(4)));
typedef unsigned short u16;
typedef unsigned long long u64;

__device__ __forceinline__ u16 f2bf(float f){
  union { float f; unsigned u; } v; v.f = f;
  unsigned r = v.u + 0x7fffu + ((v.u >> 16) & 1u);   // RTNE
  return (u16)(r >> 16);
}
__device__ __forceinline__ float sigm(float x){ return 1.0f/(1.0f + __expf(-x)); }
__device__ __forceinline__ float tanhfast(float x){ return 1.0f - 2.0f/(1.0f + __expf(2.0f*x)); }

// relaxed agent-scope coherent ops (write-through / cache-bypass, no wb/inv)
__device__ __forceinline__ void coh_store64(u16* p, u64 v){
  __hip_atomic_store((u64*)p, v, __ATOMIC_RELAXED, __HIP_MEMORY_SCOPE_AGENT);
}
__device__ __forceinline__ u64 coh_load64(const void* p){
  return __hip_atomic_load((const u64*)p, __ATOMIC_RELAXED, __HIP_MEMORY_SCOPE_AGENT);
}

// coherent b128 load, L1+L2 bypass (sc0 sc1). vmcnt is MANUALLY managed by the
// caller (counted waits) — compiler does not track these.
#define HL(dst, boff) \
  asm volatile("global_load_dwordx4 %0, %1, off offset:" boff " sc0 sc1" \
               : "=v"(dst) : "v"(haddr) : "memory");

#define MF(a,b,c) __builtin_amdgcn_mfma_f32_16x16x32_bf16((a),(b),(c),0,0,0)

// ---------------- prep kernels ----------------
__global__ void cast_f32_bf16(const float* __restrict__ src, u16* __restrict__ dst, int n4){
  int i = blockIdx.x*blockDim.x + threadIdx.x;
  const int st = gridDim.x*blockDim.x;
  for (; i < n4; i += st){
    float4 v = ((const float4*)src)[i];
    ushort4 o = make_ushort4(f2bf(v.x), f2bf(v.y), f2bf(v.z), f2bf(v.w));
    ((ushort4*)dst)[i] = o;
  }
}

__global__ void prep_bias(const float* __restrict__ bih, const float* __restrict__ bhh,
                          float* __restrict__ bc){
  int i = blockIdx.x*blockDim.x + threadIdx.x;
  if (i < G_) bc[i] = bih[i] + bhh[i];
}

// ---------------- persistent LSTM kernel ----------------
// wg = bh*128 + cg : batch-half bh (64 rows), col-group cg (8 units -> 32 gate cols).
// Per step per CU: gates[64,32] = [x_t | h][64,1536] @ Wslice^T, mfma 16x16x32 bf16.
// h broadcast via LLC coherent b128 loads, ALL 32 issued up-front (128 KB/CU in
// flight), counted vmcnt banks. Barrier = per-WG flag array (no atomics): arrive
// is one coherent store, detect is 4 waves x 64 lanes parallel flag poll.
__shared__ u16 wih_s[32*520];   // 33,280 B   [lc][512+8]
__shared__ u16 whh_s[32*1032];  // 66,048 B   [lc][1024+8]   total 99,328 B LDS

__global__ __launch_bounds__(256) void lstm_persist(
    const u16*   __restrict__ xbf,   // [B][S][I] bf16 (valid iff use_xbf)
    const float* __restrict__ xf,    // [B][S][I] f32
    const int use_xbf,
    const u16*   __restrict__ Wih,   // [G][I] bf16
    const u16*   __restrict__ Whh,   // [G][H] bf16
    const float* __restrict__ bias,  // [G]  (b_ih+b_hh)
    u16*         __restrict__ hbuf,  // [2][B][H] bf16 double buffer
    float*       __restrict__ hfin,  // [B][H] f32 final h
    const float* __restrict__ Wfc,   // [O][H]
    const float* __restrict__ bfc,   // [O]
    float*       __restrict__ out,   // [B][O]
    unsigned*    __restrict__ flags) // [NWG] arrival counters
{
  const int wg = blockIdx.x, tid = threadIdx.x;
  const int bh = wg >> 7;            // batch half: rows [bh*64, bh*64+64)
  const int cg = wg & 127;           // col group
  const int wv = tid >> 6, lane = tid & 63;
  const int n = lane & 15, g4 = lane >> 4;
  const int u0 = cg * HU;
  const int rb = bh*64 + wv*16;      // this wave's 16 batch rows

  auto colmap = [&](int lc){ return (((lc>>4)<<1) + ((lc&15)>>3))*H_ + u0 + (lc&7); };

  // all-4-wave parallel barrier wait: lane polls one flag, __all + join
  const unsigned* myflag = flags + (wv<<6) + lane;
  auto waitbar = [&](unsigned tgt){
    unsigned f = __hip_atomic_load(myflag, __ATOMIC_RELAXED, __HIP_MEMORY_SCOPE_AGENT);
    while (!__all((int)(f >= tgt))){
      __builtin_amdgcn_s_sleep(1);
      f = __hip_atomic_load(myflag, __ATOMIC_RELAXED, __HIP_MEMORY_SCOPE_AGENT);
    }
    __syncthreads();
  };

  // ---- stage W slices to LDS (once) ----
  for (int idx = tid; idx < 32*64; idx += 256){
    int lc = idx >> 6, c8 = (idx & 63) * 8;
    *(bf16x8*)(&wih_s[lc*520 + c8]) = *(const bf16x8*)(Wih + (size_t)colmap(lc)*I_ + c8);
  }
  for (int idx = tid; idx < 32*128; idx += 256){
    int lc = idx >> 7, c8 = (idx & 127) * 8;
    *(bf16x8*)(&whh_s[lc*1032 + c8]) = *(const bf16x8*)(Whh + (size_t)colmap(lc)*H_ + c8);
  }
  // ---- zero h0: this CU's output region rows [bh*64,+64) x units [u0,+8) ----
  if (tid < 64){
    u16* p = hbuf + (size_t)(bh*64 + tid)*H_ + u0;
    coh_store64(p, 0ull); coh_store64(p + 4, 0ull);
  }
  asm volatile("s_waitcnt vmcnt(0)" ::: "memory");
  __syncthreads();
  unsigned arr = 1;
  if (tid == 0) __hip_atomic_store(&flags[wg], arr, __ATOMIC_RELAXED, __HIP_MEMORY_SCOPE_AGENT);

  const float bias0 = bias[(0*2 + (n>>3))*H_ + u0 + (n&7)];   // ct0: i|f
  const float bias1 = bias[(1*2 + (n>>3))*H_ + u0 + (n&7)];   // ct1: g|o
  float cst[4] = {0.f, 0.f, 0.f, 0.f};
  const int hi = (n >> 3);
  const f32x4 z = {0.f,0.f,0.f,0.f};
  f32x4 ax0, ax1;   // x-part accumulators (precomputed, overlaps barrier wait)

  auto xpart = [&](int t){
    ax0 = z; ax1 = z;
    if (use_xbf){
      const u16* xr = xbf + (size_t)(rb + n)*(S_*I_) + (size_t)t*I_;
      #pragma unroll 4
      for (int ks = 0; ks < 16; ++ks){
        const int kk = ks*32 + g4*8;
        bf16x8 a  = *(const bf16x8*)(xr + kk);
        bf16x8 b0 = *(const bf16x8*)(&wih_s[n*520 + kk]);
        bf16x8 b1 = *(const bf16x8*)(&wih_s[(16+n)*520 + kk]);
        ax0 = MF(a, b0, ax0); ax1 = MF(a, b1, ax1);
      }
    } else {
      const float* xr = xf + (size_t)(rb + n)*(S_*I_) + (size_t)t*I_;
      #pragma unroll 2
      for (int ks = 0; ks < 16; ++ks){
        const int kk = ks*32 + g4*8;
        float4 va = *(const float4*)(xr + kk), vb = *(const float4*)(xr + kk + 4);
        bf16x8 a;
        a[0]=(short)f2bf(va.x); a[1]=(short)f2bf(va.y); a[2]=(short)f2bf(va.z); a[3]=(short)f2bf(va.w);
        a[4]=(short)f2bf(vb.x); a[5]=(short)f2bf(vb.y); a[6]=(short)f2bf(vb.z); a[7]=(short)f2bf(vb.w);
        bf16x8 b0 = *(const bf16x8*)(&wih_s[n*520 + kk]);
        bf16x8 b1 = *(const bf16x8*)(&wih_s[(16+n)*520 + kk]);
        ax0 = MF(a, b0, ax0); ax1 = MF(a, b1, ax1);
      }
    }
  };

  xpart(0);

  for (int t = 0; t < S_; ++t){
    const u16* __restrict__ hc = hbuf + (size_t)(t & 1)*(B_*H_);
    u16*       __restrict__ hn = hbuf + (size_t)((t+1) & 1)*(B_*H_);

    // ---- wait: h_t fully published (all 256 flags >= arr) ----
    waitbar(arr);

    // ---- h part: K=1024, issue ALL 32 coherent b128 loads, counted-vmcnt banks ----
    const u16* haddr = hc + (size_t)(rb + n)*H_ + g4*8;
    f32x4 acc0a = ax0, acc1a = ax1, acc0b = z, acc1b = z;
    bf16x8 hA0,hA1,hA2,hA3,hA4,hA5,hA6,hA7;
    bf16x8 hB0,hB1,hB2,hB3,hB4,hB5,hB6,hB7;
    bf16x8 hC0,hC1,hC2,hC3,hC4,hC5,hC6,hC7;
    bf16x8 hD0,hD1,hD2,hD3,hD4,hD5,hD6,hD7;

    #define CONS(hreg, ks) { \
      const int kk = (ks)*32 + g4*8; \
      bf16x8 bf0 = *(const bf16x8*)(&whh_s[n*1032 + kk]); \
      bf16x8 bf1 = *(const bf16x8*)(&whh_s[(16+n)*1032 + kk]); \
      if ((ks) & 1){ acc0b = MF(hreg, bf0, acc0b); acc1b = MF(hreg, bf1, acc1b); } \
      else         { acc0a = MF(hreg, bf0, acc0a); acc1a = MF(hreg, bf1, acc1a); } }
    #define CONS8(P, base) \
      CONS(P##0, (base)+0) CONS(P##1, (base)+1) CONS(P##2, (base)+2) CONS(P##3, (base)+3) \
      CONS(P##4, (base)+4) CONS(P##5, (base)+5) CONS(P##6, (base)+6) CONS(P##7, (base)+7)

    HL(hA0,"0")    HL(hA1,"64")   HL(hA2,"128")  HL(hA3,"192")
    HL(hA4,"256")  HL(hA5,"320")  HL(hA6,"384")  HL(hA7,"448")
    HL(hB0,"512")  HL(hB1,"576")  HL(hB2,"640")  HL(hB3,"704")
    HL(hB4,"768")  HL(hB5,"832")  HL(hB6,"896")  HL(hB7,"960")
    HL(hC0,"1024") HL(hC1,"1088") HL(hC2,"1152") HL(hC3,"1216")
    HL(hC4,"1280") HL(hC5,"1344") HL(hC6,"1408") HL(hC7,"1472")
    HL(hD0,"1536") HL(hD1,"1600") HL(hD2,"1664") HL(hD3,"1728")
    HL(hD4,"1792") HL(hD5,"1856") HL(hD6,"1920") HL(hD7,"1984")

    asm volatile("s_waitcnt vmcnt(24)" ::: "memory");
    __builtin_amdgcn_sched_barrier(0);
    CONS8(hA, 0)
    asm volatile("s_waitcnt vmcnt(16)" ::: "memory");
    __builtin_amdgcn_sched_barrier(0);
    CONS8(hB, 8)
    asm volatile("s_waitcnt vmcnt(8)" ::: "memory");
    __builtin_amdgcn_sched_barrier(0);
    CONS8(hC, 16)
    asm volatile("s_waitcnt vmcnt(0)" ::: "memory");
    __builtin_amdgcn_sched_barrier(0);
    CONS8(hD, 24)

    #undef CONS8
    #undef CONS

    f32x4 acc0 = acc0a + acc0b;
    f32x4 acc1 = acc1a + acc1b;

    // ---- gates / state update (D: col=lane&15, row=(lane>>4)*4+reg) ----
    #pragma unroll
    for (int reg = 0; reg < 4; ++reg){
      float p0 = acc0[reg] + bias0;     // ct0: n<8 -> i(unit n), n>=8 -> f(unit n-8)
      float p1 = acc1[reg] + bias1;     // ct1: g / o
      float q0 = __shfl_xor(p0, 8);
      float q1 = __shfl_xor(p1, 8);
      float ip = hi ? q0 : p0;
      float fp = hi ? p0 : q0;
      float gp = hi ? q1 : p1;
      float op = hi ? p1 : q1;
      float iv = sigm(ip), fv = sigm(fp), gv = tanhfast(gp), ov = sigm(op);
      float c = fv*cst[reg] + iv*gv;
      cst[reg] = c;
      float h = ov * tanhfast(c);
      const int r = rb + g4*4 + reg;

      unsigned v16 = f2bf(h);
      unsigned pr  = v16 | (__shfl_xor(v16, 1) << 16);
      unsigned pr2 = __shfl_xor(pr, 2);
      if (hi == 0 && (n & 3) == 0){                      // lanes 0,4: units n..n+3
        u64 q = (u64)pr | ((u64)pr2 << 32);
        coh_store64(hn + (size_t)r*H_ + u0 + n, q);
      }
      if (t == S_-1){
        unsigned fb = __float_as_uint(h);
        unsigned fo = __shfl_xor(fb, 1);
        if (hi == 0 && (n & 1) == 0){                    // lanes 0,2,4,6: f32 pairs
          u64 q = (u64)fb | ((u64)fo << 32);
          __hip_atomic_store((u64*)(hfin + (size_t)r*H_ + u0 + n), q,
                             __ATOMIC_RELAXED, __HIP_MEMORY_SCOPE_AGENT);
        }
      }
    }

    // ---- arrive: drain stores, then one fire-and-forget flag store ----
    asm volatile("s_waitcnt vmcnt(0)" ::: "memory");
    __syncthreads();
    ++arr;
    if (tid == 0) __hip_atomic_store(&flags[wg], arr, __ATOMIC_RELAXED, __HIP_MEMORY_SCOPE_AGENT);

    if (t < S_-1) xpart(t+1);    // overlaps other WGs' straggle + barrier latency
  }

  // ---- final wait: hfin fully published ----
  waitbar(arr);

  // ---- fused FC epilogue: out[b] = hfin[b] @ Wfc^T + bfc ----
  {
    const int b = wg & 127;
    const int o = (wg >> 7)*64 + (tid >> 2);
    const int qtr = tid & 3;
    const float* hb = hfin + (size_t)b*H_ + qtr*256;
    const float* wb = Wfc + (size_t)o*H_ + qtr*256;
    float s = 0.f;
    #pragma unroll 8
    for (int j = 0; j < 128; ++j){
      u64 q = coh_load64(hb + j*2);
      float a0 = __uint_as_float((unsigned)q);
      float a1 = __uint_as_float((unsigned)(q >> 32));
      float2 w = *(const float2*)(wb + j*2);
      s += a0*w.x + a1*w.y;
    }
    s += __shfl_xor(s, 1);
    s += __shfl_xor(s, 2);
    if (qtr == 0) out[(size_t)b*O_ + o] = s + bfc[o];
  }
}

// ---------------- launcher ----------------
// ws layout (256-aligned):
//   [0)          Wih bf16   4,194,304
//   [4194304)    Whh bf16   8,388,608
//   [12582912)   bias f32      16,384
//   [12599296)   hbuf bf16    524,288
//   [13123584)   hfin f32     524,288
//   [13647872)   flags u32      1,024
//   [13648896)   x bf16    67,108,864   (optional: only if ws_size allows)
extern "C" void kernel_launch(void* const* d_in, const int* in_sizes, int n_in,
                              void* d_out, int out_size, void* d_ws, size_t ws_size,
                              hipStream_t stream) {
  const float* x   = (const float*)d_in[0];
  const float* Wih = (const float*)d_in[1];
  const float* Whh = (const float*)d_in[2];
  const float* bih = (const float*)d_in[3];
  const float* bhh = (const float*)d_in[4];
  const float* Wfc = (const float*)d_in[5];
  const float* bfc = (const float*)d_in[6];
  float* out = (float*)d_out;

  char* ws = (char*)d_ws;
  u16*      wih_bf = (u16*)     (ws + 0);
  u16*      whh_bf = (u16*)     (ws + 4194304);
  float*    biasc  = (float*)   (ws + 12582912);
  u16*      hbuf   = (u16*)     (ws + 12599296);
  float*    hfin   = (float*)   (ws + 13123584);
  unsigned* flags  = (unsigned*)(ws + 13647872);
  u16*      xbf    = (u16*)     (ws + 13648896);
  const int use_xbf = (ws_size >= (size_t)13648896 + 67108864) ? 1 : 0;

  hipMemsetAsync(flags, 0, 1024, stream);
  cast_f32_bf16<<<1024, 256, 0, stream>>>(Wih, wih_bf, (G_*I_)/4);
  cast_f32_bf16<<<2048, 256, 0, stream>>>(Whh, whh_bf, (G_*H_)/4);
  prep_bias<<<16, 256, 0, stream>>>(bih, bhh, biasc);
  if (use_xbf)
    cast_f32_bf16<<<2048, 256, 0, stream>>>(x, xbf, (B_*S_*I_)/4);

  lstm_persist<<<NWG, 256, 0, stream>>>(xbf, x, use_xbf, wih_bf, whh_bf, biasc,
                                        hbuf, hfin, Wfc, bfc, out, flags);
}